// Round 1
// baseline (100.206 us; speedup 1.0000x reference)
//
#include <hip/hip_runtime.h>
#include <hip/hip_bf16.h>

// SparseLinear: out[b,l] = dot(embed[b,:], weight[shortlist[b,l],:]) + bias[shortlist[b,l]]
// B=256, L=1000, D=512, V=670092. Memory-bound gather of 2KB rows.

#define BB 256
#define LL 1000
#define DD 512
#define LPB 40   // l's per block (4 waves x 10 iterations)

__global__ __launch_bounds__(256) void sparse_linear_kernel(
    const float* __restrict__ embed,      // [B, D]
    const int*   __restrict__ shortlist,  // [B, L]
    const float* __restrict__ weight,     // [V, D]
    const float* __restrict__ bias,       // [V, 1]
    float*       __restrict__ out)        // [B, L]
{
    const int b    = blockIdx.y;
    const int lane = threadIdx.x & 63;
    const int wave = threadIdx.x >> 6;   // 0..3

    // Each lane holds 8 embed floats in registers: embed[b, lane*8 .. lane*8+7].
    // 64 lanes x 8 = 512 = D. Loaded once per block; L1 serves the 4 waves.
    const float4* e4 = reinterpret_cast<const float4*>(embed + (size_t)b * DD + lane * 8);
    const float4 e0 = e4[0];
    const float4 e1 = e4[1];

    const int l_base = blockIdx.x * LPB;
    const int l_end  = min(LL, l_base + LPB);

    for (int l = l_base + wave; l < l_end; l += 4) {
        const int idx = shortlist[(size_t)b * LL + l];
        const float4* w4 = reinterpret_cast<const float4*>(weight + (size_t)idx * DD + lane * 8);
        const float4 w0 = w4[0];
        const float4 w1 = w4[1];

        float s = e0.x * w0.x + e0.y * w0.y + e0.z * w0.z + e0.w * w0.w
                + e1.x * w1.x + e1.y * w1.y + e1.z * w1.z + e1.w * w1.w;

        // 64-lane wave reduction
        #pragma unroll
        for (int off = 32; off > 0; off >>= 1)
            s += __shfl_down(s, off);

        if (lane == 0)
            out[(size_t)b * LL + l] = s + bias[idx];
    }
}

extern "C" void kernel_launch(void* const* d_in, const int* in_sizes, int n_in,
                              void* d_out, int out_size, void* d_ws, size_t ws_size,
                              hipStream_t stream) {
    const float* embed     = (const float*)d_in[0];  // [256, 512] f32
    const int*   shortlist = (const int*)  d_in[1];  // [256, 1000] int
    const float* weight    = (const float*)d_in[2];  // [670092, 512] f32
    const float* bias      = (const float*)d_in[3];  // [670092, 1] f32
    float*       out       = (float*)d_out;          // [256, 1000] f32

    dim3 grid((LL + LPB - 1) / LPB, BB);
    sparse_linear_kernel<<<grid, 256, 0, stream>>>(embed, shortlist, weight, bias, out);
}

// Round 2
// 86.096 us; speedup vs baseline: 1.1639x; 1.1639x over previous
//
#include <hip/hip_runtime.h>
#include <hip/hip_bf16.h>

// SparseLinear: out[b,l] = dot(embed[b,:], weight[shortlist[b,l],:]) + bias[shortlist[b,l]]
// B=256, L=1000, D=512, V=670092. Memory-bound gather of 2KB rows.
// R2: prefetch per-wave indices (kill dependent idx load), 2 rows in flight,
//     early bias loads.

#define BB 256
#define LL 1000
#define DD 512
#define LPB 40    // l's per block: 4 waves x 10 iterations
#define ITERS 10  // rows per wave

__global__ __launch_bounds__(256) void sparse_linear_kernel(
    const float* __restrict__ embed,      // [B, D]
    const int*   __restrict__ shortlist,  // [B, L]
    const float* __restrict__ weight,     // [V, D]
    const float* __restrict__ bias,       // [V, 1]
    float*       __restrict__ out)        // [B, L]
{
    const int b    = blockIdx.y;
    const int lane = threadIdx.x & 63;
    const int wave = threadIdx.x >> 6;   // 0..3

    // Each lane holds 8 embed floats: embed[b, lane*8 .. lane*8+7].
    const float4* e4 = reinterpret_cast<const float4*>(embed + (size_t)b * DD + lane * 8);
    const float4 e0 = e4[0];
    const float4 e1 = e4[1];

    // Wave handles l = lbase + 4*i, i in [0,10).
    const int lbase = blockIdx.x * LPB + wave;

    // Prefetch all 10 indices for this wave in one shot (lanes 0..9).
    int pidx = 0;
    if (lane < ITERS)
        pidx = shortlist[(size_t)b * LL + lbase + 4 * lane];

    #pragma unroll
    for (int i = 0; i < ITERS; i += 2) {
        const int idx0 = __shfl(pidx, i);
        const int idx1 = __shfl(pidx, i + 1);

        // Issue bias loads early; latency hides under the row fetches.
        float bval = 0.0f;
        if (lane == 0) bval = bias[idx0];
        if (lane == 1) bval = bias[idx1];

        const float4* wa = reinterpret_cast<const float4*>(weight + (size_t)idx0 * DD + lane * 8);
        const float4* wb = reinterpret_cast<const float4*>(weight + (size_t)idx1 * DD + lane * 8);
        const float4 a0 = wa[0];
        const float4 a1 = wa[1];
        const float4 c0 = wb[0];
        const float4 c1 = wb[1];

        float s0 = e0.x * a0.x + e0.y * a0.y + e0.z * a0.z + e0.w * a0.w
                 + e1.x * a1.x + e1.y * a1.y + e1.z * a1.z + e1.w * a1.w;
        float s1 = e0.x * c0.x + e0.y * c0.y + e0.z * c0.z + e0.w * c0.w
                 + e1.x * c1.x + e1.y * c1.y + e1.z * c1.z + e1.w * c1.w;

        // 64-lane wave reductions (both rows together).
        #pragma unroll
        for (int off = 32; off > 0; off >>= 1) {
            s0 += __shfl_down(s0, off);
            s1 += __shfl_down(s1, off);
        }

        const float b1v = __shfl(bval, 1);
        if (lane == 0) {
            out[(size_t)b * LL + lbase + 4 * i]       = s0 + bval;
            out[(size_t)b * LL + lbase + 4 * (i + 1)] = s1 + b1v;
        }
    }
}

extern "C" void kernel_launch(void* const* d_in, const int* in_sizes, int n_in,
                              void* d_out, int out_size, void* d_ws, size_t ws_size,
                              hipStream_t stream) {
    const float* embed     = (const float*)d_in[0];  // [256, 512] f32
    const int*   shortlist = (const int*)  d_in[1];  // [256, 1000] int
    const float* weight    = (const float*)d_in[2];  // [670092, 512] f32
    const float* bias      = (const float*)d_in[3];  // [670092, 1] f32
    float*       out       = (float*)d_out;          // [256, 1000] f32

    dim3 grid((LL + LPB - 1) / LPB, BB);
    sparse_linear_kernel<<<grid, 256, 0, stream>>>(embed, shortlist, weight, bias, out);
}